// Round 2
// baseline (247.833 us; speedup 1.0000x reference)
//
#include <hip/hip_runtime.h>
#include <hip/hip_cooperative_groups.h>

namespace cg = cooperative_groups;

typedef __attribute__((ext_vector_type(8))) short short8;
typedef __attribute__((ext_vector_type(4))) float floatx4;

#define B_    8
#define CIN   256
#define NSP   2048   // T*H*W
#define FF    512
#define COUT  256

__device__ __forceinline__ unsigned short f2bf(float f) {
  unsigned int u = __float_as_uint(f);
  u += 0x7fffu + ((u >> 16) & 1u);   // RNE
  return (unsigned short)(u >> 16);
}

// One cooperative kernel, 256 blocks x 256 threads (1 block/CU).
// Phase 1: blocks 0..31 -> M = Wout@Wv (f32->bf16); blocks 32..255 -> x
//          transpose to XT[b][n][c] bf16. Block 0 zeroes stats.
// Phase 2: 128x128 MFMA GEMM o = M@x, fused bias+relu+residual; y kept in
//          the accumulator registers; BN partial sums -> global atomics.
// Phase 3: finalize scale/shift per block, write out from registers.
__global__ __launch_bounds__(256) void fused_all(
    const float* __restrict__ x, const float* __restrict__ Wv,
    const float* __restrict__ Wout, const float* __restrict__ bout,
    const float* __restrict__ gamma, const float* __restrict__ beta,
    unsigned short* __restrict__ Mb, unsigned short* __restrict__ XT,
    float* __restrict__ stats, float* __restrict__ out)
{
  __shared__ float lds[64 * 65];     // phase-1 staging (M rows / transpose tile)
  __shared__ float ls[128], lq[128]; // phase-2 stats, phase-3 scale/shift
  const int tid  = threadIdx.x;
  const int bx   = blockIdx.x;
  const int lane = tid & 63;
  const int wave = tid >> 6;
  const int m16  = lane & 15;
  const int q    = lane >> 4;

  if (tid < 128) { ls[tid] = 0.f; lq[tid] = 0.f; }

  // ------------------------------ Phase 1 ------------------------------
  if (bx < 32) {
    if (bx == 0) { stats[tid] = 0.f; stats[256 + tid] = 0.f; }
    const int rbase = bx * 8;
    #pragma unroll
    for (int i = 0; i < 16; ++i)
      lds[i * 256 + tid] = Wout[(size_t)rbase * 512 + i * 256 + tid];
    __syncthreads();
    float a8[8] = {0.f,0.f,0.f,0.f,0.f,0.f,0.f,0.f};
    #pragma unroll 8
    for (int f = 0; f < 512; ++f) {
      float w = Wv[(size_t)f * 256 + tid];
      #pragma unroll
      for (int j = 0; j < 8; ++j) a8[j] += lds[j * 512 + f] * w;
    }
    #pragma unroll
    for (int j = 0; j < 8; ++j)
      Mb[(size_t)(rbase + j) * 256 + tid] = f2bf(a8[j]);
  } else {
    for (int t = bx - 32; t < 1024; t += 224) {
      __syncthreads();   // LDS reuse guard across iterations
      const int tb  = t >> 7;
      const int rem = t & 127;
      const int n0  = (rem & 31) * 64;
      const int c0  = (rem >> 5) * 64;
      const float* xb = x + (size_t)tb * CIN * NSP;
      const int n_l  = tid & 63;
      const int c_l0 = tid >> 6;
      #pragma unroll
      for (int p = 0; p < 16; ++p) {
        int c_l = c_l0 + p * 4;
        lds[c_l * 65 + n_l] = xb[(size_t)(c0 + c_l) * NSP + n0 + n_l];
      }
      __syncthreads();
      const int cp   = tid & 31;
      const int n_l2 = tid >> 5;
      unsigned int* XT32 = (unsigned int*)XT;
      #pragma unroll
      for (int p = 0; p < 8; ++p) {
        int nn = n_l2 + p * 8;
        unsigned short lo = f2bf(lds[(2 * cp)     * 65 + nn]);
        unsigned short hi = f2bf(lds[(2 * cp + 1) * 65 + nn]);
        XT32[((size_t)tb * NSP + n0 + nn) * 128 + (c0 >> 1) + cp] =
            (unsigned int)lo | ((unsigned int)hi << 16);
      }
    }
  }

  __threadfence();
  cg::this_grid().sync();

  // ------------------------------ Phase 2 ------------------------------
  const int b    = bx >> 5;
  const int ocb  = ((bx >> 4) & 1) * 128;
  const int nb   = (bx & 15) * 128;
  const int wocb = ocb + (wave & 1) * 64;
  const int wnb  = nb + (wave >> 1) * 64;

  floatx4 acc[4][4];
  #pragma unroll
  for (int i = 0; i < 4; ++i)
    #pragma unroll
    for (int j = 0; j < 4; ++j)
      acc[i][j] = (floatx4){0.f, 0.f, 0.f, 0.f};

  const unsigned short* Abase = Mb + (size_t)(wocb + m16) * 256 + q * 8;
  const unsigned short* Bbase = XT + ((size_t)b * NSP + wnb + m16) * 256 + q * 8;

  #pragma unroll
  for (int kk = 0; kk < 8; ++kk) {
    short8 av[4], bv[4];
    #pragma unroll
    for (int t = 0; t < 4; ++t) {
      av[t] = *(const short8*)(Abase + (size_t)t * 16 * 256 + kk * 32);
      bv[t] = *(const short8*)(Bbase + (size_t)t * 16 * 256 + kk * 32);
    }
    #pragma unroll
    for (int i = 0; i < 4; ++i)
      #pragma unroll
      for (int j = 0; j < 4; ++j)
        acc[i][j] = __builtin_amdgcn_mfma_f32_16x16x32_bf16(av[i], bv[j], acc[i][j], 0, 0, 0);
  }

  __syncthreads();   // ls/lq zeros ready

  // D layout: col(n) = lane&15, row(oc) = q*4 + reg. Keep y in acc.
  #pragma unroll
  for (int ti = 0; ti < 4; ++ti) {
    #pragma unroll
    for (int r = 0; r < 4; ++r) {
      const int oc = wocb + ti * 16 + q * 4 + r;
      const float bo = bout[oc];
      float s = 0.f, s2 = 0.f;
      #pragma unroll
      for (int tj = 0; tj < 4; ++tj) {
        const int n = wnb + tj * 16 + m16;
        float o = acc[ti][tj][r] + bo;
        o = fmaxf(o, 0.f);
        const size_t gidx = ((size_t)(b * COUT + oc)) * NSP + n;
        float y = x[gidx] + o;   // residual (L2/L3-hot)
        acc[ti][tj][r] = y;      // keep y resident in registers
        s += y;
        s2 += y * y;
      }
      #pragma unroll
      for (int d = 1; d < 16; d <<= 1) {
        s  += __shfl_xor(s, d, 64);
        s2 += __shfl_xor(s2, d, 64);
      }
      if (m16 == 0) {
        atomicAdd(&ls[oc - ocb], s);
        atomicAdd(&lq[oc - ocb], s2);
      }
    }
  }
  __syncthreads();
  if (tid < 128) {
    atomicAdd(&stats[ocb + tid], ls[tid]);
    atomicAdd(&stats[256 + ocb + tid], lq[tid]);
  }

  __threadfence();
  cg::this_grid().sync();

  // ------------------------------ Phase 3 ------------------------------
  if (tid < 128) {
    const int oc = ocb + tid;
    const float inv_n = 1.f / 16384.f;
    float m = stats[oc] * inv_n;
    float v = stats[256 + oc] * inv_n - m * m;
    float inv = rsqrtf(v + 1e-5f);
    float sc = gamma[oc] * inv;
    ls[tid] = sc;
    lq[tid] = beta[oc] - m * sc;
  }
  __syncthreads();

  #pragma unroll
  for (int ti = 0; ti < 4; ++ti) {
    #pragma unroll
    for (int r = 0; r < 4; ++r) {
      const int ocl = (wave & 1) * 64 + ti * 16 + q * 4 + r;
      const int oc  = ocb + ocl;
      const float sc = ls[ocl];
      const float sh = lq[ocl];
      #pragma unroll
      for (int tj = 0; tj < 4; ++tj) {
        const int n = wnb + tj * 16 + m16;
        const size_t gidx = ((size_t)(b * COUT + oc)) * NSP + n;
        out[gidx] = acc[ti][tj][r] * sc + sh;
      }
    }
  }
}

extern "C" void kernel_launch(void* const* d_in, const int* in_sizes, int n_in,
                              void* d_out, int out_size, void* d_ws, size_t ws_size,
                              hipStream_t stream) {
  const float* x     = (const float*)d_in[0];
  // d_in[1] = Wk, d_in[2] = Wq : mathematically dead (softmax rows sum to 1,
  // so sum(attn, axis=2) == 1 and agg == V).
  const float* Wv    = (const float*)d_in[3];
  const float* Wout  = (const float*)d_in[4];
  const float* bout  = (const float*)d_in[5];
  const float* gamma = (const float*)d_in[6];
  const float* beta  = (const float*)d_in[7];
  float* out = (float*)d_out;

  char* w = (char*)d_ws;
  unsigned short* Mb = (unsigned short*)w;                // 128 KiB
  unsigned short* XT = (unsigned short*)(w + 131072);     // 8 MiB
  float* stats = (float*)(w + 131072 + 8388608);          // 512 f32

  void* args[] = {(void*)&x, (void*)&Wv, (void*)&Wout, (void*)&bout,
                  (void*)&gamma, (void*)&beta, (void*)&Mb, (void*)&XT,
                  (void*)&stats, (void*)&out};
  hipLaunchCooperativeKernel((const void*)fused_all, dim3(256), dim3(256),
                             args, 0, stream);
}

// Round 3
// 114.048 us; speedup vs baseline: 2.1731x; 2.1731x over previous
//
#include <hip/hip_runtime.h>

typedef __attribute__((ext_vector_type(8))) short short8;
typedef __attribute__((ext_vector_type(4))) float floatx4;

#define CIN  256
#define NSP  2048   // T*H*W
#define COUT 256

__device__ __forceinline__ unsigned short f2bf_rne(float f) {
  unsigned int u = __float_as_uint(f);
  u += 0x7fffu + ((u >> 16) & 1u);
  return (unsigned short)(u >> 16);
}

// pack two f32 -> bf16x2 (round-half-up: +0x8000 then take hi16) in 3 VALU
__device__ __forceinline__ unsigned int pack_bf16_hu(float lo, float hi) {
  unsigned int a = __float_as_uint(lo) + 0x8000u;
  unsigned int b = __float_as_uint(hi) + 0x8000u;
  // result bytes [b.3 b.2 a.3 a.2] -> low half = lo's bf16, high = hi's
  return __builtin_amdgcn_perm(b, a, 0x07060302u);
}

// ---------------------------------------------------------------------------
// K1: M = Wout @ Wv (bf16). 256 blocks (1 row each) x 1024 threads.
// Waves split the f(=512) reduction 4 ways; LDS reduce. Block 0 zeroes stats.
// ---------------------------------------------------------------------------
__global__ __launch_bounds__(1024) void k1_m(
    const float* __restrict__ Wv, const float* __restrict__ Wout,
    unsigned short* __restrict__ Mb, float* __restrict__ stats)
{
  __shared__ float ws[512];
  __shared__ float red[4][256];
  const int tid = threadIdx.x;
  const int r   = blockIdx.x;
  if (r == 0 && tid < 512) stats[tid] = 0.f;
  if (tid < 512) ws[tid] = Wout[(size_t)r * 512 + tid];
  __syncthreads();
  const int c  = tid & 255;
  const int fs = tid >> 8;            // constant per wave -> ws[f] broadcast
  float acc = 0.f;
  #pragma unroll 16
  for (int f0 = 0; f0 < 128; ++f0) {
    int f = fs * 128 + f0;
    acc += ws[f] * Wv[(size_t)f * 256 + c];   // coalesced, L2-hot
  }
  red[fs][c] = acc;
  __syncthreads();
  if (tid < 256) {
    float s = red[0][tid] + red[1][tid] + red[2][tid] + red[3][tid];
    Mb[(size_t)r * 256 + tid] = f2bf_rne(s);
  }
}

// ---------------------------------------------------------------------------
// K2: o = M @ x per batch via bf16 MFMA; B-fragments built in-register from
// f32 x (no transpose pass, no LDS staging, no K-loop barriers).
// Fused bias+relu+residual; f32 y -> out (d_out); BN partial sums -> stats.
// grid (32 nb, 2 ocb, 8 b) = 512 blocks; block = 4 waves; wave tile 64oc x 32n.
// ---------------------------------------------------------------------------
__global__ __launch_bounds__(256) void k2_gemm(
    const float* __restrict__ x, const unsigned short* __restrict__ Mb,
    const float* __restrict__ bout, float* __restrict__ stats,
    float* __restrict__ out)
{
  __shared__ float ls[128], lq[128];
  const int tid  = threadIdx.x;
  const int lane = tid & 63;
  const int wave = tid >> 6;
  const int m16  = lane & 15;
  const int q    = lane >> 4;
  const int nb   = blockIdx.x * 64;
  const int ocb  = blockIdx.y * 128;
  const int b    = blockIdx.z;
  const int wocb = ocb + (wave & 1) * 64;   // wave's 64 oc rows
  const int wnb  = nb + (wave >> 1) * 32;   // wave's 32 n cols

  if (tid < 128) { ls[tid] = 0.f; lq[tid] = 0.f; }

  floatx4 acc[4][2];
  #pragma unroll
  for (int i = 0; i < 4; ++i)
    #pragma unroll
    for (int j = 0; j < 2; ++j)
      acc[i][j] = (floatx4){0.f, 0.f, 0.f, 0.f};

  const unsigned short* Ab = Mb + (size_t)(wocb + m16) * 256 + q * 8;
  const float* xb = x + (size_t)b * CIN * NSP;
  const float* Bb = xb + (size_t)(q * 8) * NSP + wnb + m16;

  #pragma unroll
  for (int kk = 0; kk < 8; ++kk) {
    short8 av[4];
    #pragma unroll
    for (int ti = 0; ti < 4; ++ti)
      av[ti] = *(const short8*)(Ab + (size_t)ti * 16 * 256 + kk * 32);
    short8 bv[2];
    #pragma unroll
    for (int tj = 0; tj < 2; ++tj) {
      const float* bp = Bb + (size_t)(kk * 32) * NSP + tj * 16;
      union { unsigned int u[4]; short8 v; } p;
      #pragma unroll
      for (int j = 0; j < 4; ++j) {
        float f0 = bp[(size_t)(2 * j) * NSP];       // c = kk*32+q*8+2j
        float f1 = bp[(size_t)(2 * j + 1) * NSP];
        p.u[j] = pack_bf16_hu(f0, f1);
      }
      bv[tj] = p.v;
    }
    #pragma unroll
    for (int ti = 0; ti < 4; ++ti)
      #pragma unroll
      for (int tj = 0; tj < 2; ++tj)
        acc[ti][tj] = __builtin_amdgcn_mfma_f32_16x16x32_bf16(av[ti], bv[tj], acc[ti][tj], 0, 0, 0);
  }

  __syncthreads();  // ls/lq zeros ready

  // D layout: col(n)=lane&15, row(oc within 16-tile)=q*4+reg
  #pragma unroll
  for (int ti = 0; ti < 4; ++ti) {
    #pragma unroll
    for (int r = 0; r < 4; ++r) {
      const int ocl = (wave & 1) * 64 + ti * 16 + q * 4 + r;
      const int oc  = ocb + ocl;
      const float bo = bout[oc];
      float s = 0.f, s2 = 0.f;
      #pragma unroll
      for (int tj = 0; tj < 2; ++tj) {
        const int n = wnb + tj * 16 + m16;
        const size_t gidx = ((size_t)(b * COUT + oc)) * NSP + n;
        float o = fmaxf(acc[ti][tj][r] + bo, 0.f);
        float y = x[gidx] + o;        // residual: row is L1/L2-hot (B-loads)
        out[gidx] = y;                // f32, full 64B sectors per quad
        s += y;
        s2 += y * y;
      }
      #pragma unroll
      for (int d = 1; d < 16; d <<= 1) {  // stays within 16-lane group
        s  += __shfl_xor(s, d, 64);
        s2 += __shfl_xor(s2, d, 64);
      }
      if (m16 == 0) {
        atomicAdd(&ls[ocl], s);
        atomicAdd(&lq[ocl], s2);
      }
    }
  }
  __syncthreads();
  if (tid < 128) {
    atomicAdd(&stats[ocb + tid], ls[tid]);
    atomicAdd(&stats[256 + ocb + tid], lq[tid]);
  }
}

// ---------------------------------------------------------------------------
// K3: normalize d_out in place. 2048 blocks = one (b,oc) row of 2048 each.
// scale/shift computed redundantly per thread (broadcast loads).
// ---------------------------------------------------------------------------
__global__ __launch_bounds__(256) void k3_norm(
    const float* __restrict__ stats, const float* __restrict__ gamma,
    const float* __restrict__ beta, float* __restrict__ out)
{
  const int row = blockIdx.x;       // b*256 + oc
  const int oc  = row & 255;
  const float inv_n = 1.f / 16384.f;
  const float m  = stats[oc] * inv_n;
  const float v  = stats[256 + oc] * inv_n - m * m;
  const float sc = gamma[oc] * rsqrtf(v + 1e-5f);
  const float sh = beta[oc] - m * sc;
  float* p = out + (size_t)row * 2048 + threadIdx.x * 8;
  float4 a = *(const float4*)p;
  float4 c = *(const float4*)(p + 4);
  a.x = a.x * sc + sh; a.y = a.y * sc + sh;
  a.z = a.z * sc + sh; a.w = a.w * sc + sh;
  c.x = c.x * sc + sh; c.y = c.y * sc + sh;
  c.z = c.z * sc + sh; c.w = c.w * sc + sh;
  *(float4*)p = a;
  *(float4*)(p + 4) = c;
}

extern "C" void kernel_launch(void* const* d_in, const int* in_sizes, int n_in,
                              void* d_out, int out_size, void* d_ws, size_t ws_size,
                              hipStream_t stream) {
  const float* x     = (const float*)d_in[0];
  // d_in[1]=Wk, d_in[2]=Wq: dead — softmax rows sum to 1, so agg == V,
  // and o = Wout@(Wv@x) = (Wout@Wv)@x = M@x.
  const float* Wv    = (const float*)d_in[3];
  const float* Wout  = (const float*)d_in[4];
  const float* bout  = (const float*)d_in[5];
  const float* gamma = (const float*)d_in[6];
  const float* beta  = (const float*)d_in[7];
  float* out = (float*)d_out;

  char* w = (char*)d_ws;
  unsigned short* Mb = (unsigned short*)w;      // 128 KiB bf16 M
  float* stats = (float*)(w + 131072);          // 512 f32 (zeroed by K1)

  hipLaunchKernelGGL(k1_m,    dim3(256),       dim3(1024), 0, stream,
                     Wv, Wout, Mb, stats);
  hipLaunchKernelGGL(k2_gemm, dim3(32, 2, 8),  dim3(256),  0, stream,
                     x, Mb, bout, stats, out);
  hipLaunchKernelGGL(k3_norm, dim3(2048),      dim3(256),  0, stream,
                     stats, gamma, beta, out);
}